// Round 1
// baseline (98.904 us; speedup 1.0000x reference)
//
#include <hip/hip_runtime.h>

// ---------------------------------------------------------------------------
// Conv2dfft == 3x3 SAME cross-correlation conv (pad=1) + bias.
// N=32, C=128, F=128, H=W=32.  Implicit-GEMM with bf16 MFMA 16x16x32.
//   GEMM per tap (p,q):  D[f][s] += W[f,c,p,q] * X[c, s_shifted]
//   A-operand = weight  (M = f),  B-operand = x (N = spatial) -> coalesced C.
// ---------------------------------------------------------------------------

typedef short bf16x8 __attribute__((ext_vector_type(8)));   // 8 bf16 (4 VGPR)
typedef float f32x4  __attribute__((ext_vector_type(4)));   // MFMA 16x16 acc

__device__ __forceinline__ short f2bf(float f) {            // RNE fp32->bf16
  unsigned u = __builtin_bit_cast(unsigned, f);
  u = (u + 0x7fffu + ((u >> 16) & 1u)) >> 16;
  return (short)u;
}

__device__ __forceinline__ void gload_lds16(const void* g, void* l) {
  // 16B per lane, LDS dst = wave-uniform base + lane*16
  __builtin_amdgcn_global_load_lds(
      (const __attribute__((address_space(1))) unsigned int*)g,
      (__attribute__((address_space(3))) unsigned int*)l,
      16, 0, 0);
}

// ---------------------------------------------------------------------------
// Prepass: weight (F,C,3,3) fp32  ->  bf16, layout [chunk(4)][p][q][f(128)][40]
// c-chunk of 32 channels stored c-contiguous (stride padded 32->40 shorts so
// the main kernel's strided ds_read_b128 is conflict-free; pad never read).
// 147456 useful elements -> 576 blocks x 256 threads.
// ---------------------------------------------------------------------------
__global__ __launch_bounds__(256) void conv_wprep(const float* __restrict__ w,
                                                  short* __restrict__ bc) {
  int tid = blockIdx.x * 256 + threadIdx.x;     // [0, 147456)
  int ci  = tid & 31;                           // c within chunk
  int f   = (tid >> 5) & 127;
  int grp = tid >> 12;                          // chunk*9 + p*3 + q, [0,36)
  int pq  = grp % 9;
  int chunk = grp / 9;
  int p = pq / 3, q = pq % 3;
  int c = chunk * 32 + ci;
  float v = w[((f * 128 + c) * 3 + p) * 3 + q];
  bc[(grp * 128 + f) * 40 + ci] = f2bf(v);
}

// ---------------------------------------------------------------------------
// Main kernel: 256 blocks x 256 threads (4 waves).
// Block = image n_img, output rows h0..h0+3, all 32 cols, all 128 f.
// Wave (2x2): f_off = (wv&1)*64, spatial row base = (wv>>1)*2.
// K-loop: 4 chunks of 32 channels; per chunk stage x tile once, then 3
// p-phases each staging 3*(q)*128*40 weights via global_load_lds.
// ---------------------------------------------------------------------------
__global__ __launch_bounds__(256, 1) void conv_main(
    const float* __restrict__ x, const short* __restrict__ bc,
    const float* __restrict__ bias, float* __restrict__ out) {
  __shared__ __align__(16) short ws[3 * 128 * 40];   // 30720 B: 3 taps (q) of weights
  __shared__ __align__(16) short xs[6 * 34 * 40];    // 16320 B: [row][col][c] bf16 x tile

  const int t    = threadIdx.x;
  const int lane = t & 63;
  const int wv   = t >> 6;
  const int n_img = blockIdx.x >> 3;
  const int h0    = (blockIdx.x & 7) << 2;

  const int l15  = lane & 15;
  const int quad = lane >> 4;
  const int f_off  = (wv & 1) * 64;   // wave's f range [f_off, f_off+64)
  const int s_rowb = (wv >> 1) * 2;   // wave's out-row base (2 rows)

  // Zero halo columns (col 0 == w=-1, col 33 == w=32); written once, reused
  // every chunk (staging only rewrites cols 1..32).
  if (t < 192) {
    int r = t >> 5, ci = t & 31;
    xs[(r * 34 + 0)  * 40 + ci] = 0;
    xs[(r * 34 + 33) * 40 + ci] = 0;
  }

  f32x4 acc[4][4] = {};               // [mt(f)][nt(spatial)] 16x16 tiles

  // x staging thread mapping: w = t&31 (coalesced), g = t>>5 picks (r,ci)
  const int w_ = t & 31;
  const int g  = t >> 5;
  const float* xb = x + ((n_img * 128) * 32 + (h0 - 1)) * 32 + w_;

  for (int chunk = 0; chunk < 4; ++chunk) {
    const int c0 = chunk * 32;
    // ---- stage x tile: rows h0-1..h0+4, 32 channels, fp32->bf16 transpose ----
#pragma unroll
    for (int i = 0; i < 24; ++i) {
      int comb = i * 8 + g;                    // 0..191 = r*32 + ci
      int r = comb >> 5, ci = comb & 31;
      int hr = h0 - 1 + r;
      float v = 0.f;
      if (hr >= 0 && hr < 32) v = xb[(c0 + ci) * 1024 + r * 32];
      xs[(r * 34 + (w_ + 1)) * 40 + ci] = f2bf(v);
    }
#pragma unroll
    for (int p = 0; p < 3; ++p) {
      // ---- stage 3 q-taps of weights for (chunk,p): 30720 contiguous bytes ----
      const char* src = (const char*)bc + (chunk * 3 + p) * 30720;
      for (int i = wv; i < 30; i += 4)
        gload_lds16(src + i * 1024 + lane * 16, (char*)ws + i * 1024);
      __syncthreads();   // drains global_load_lds (vmcnt) + xs writes
      // ---- compute: 3 q-taps x 16 MFMAs ----
#pragma unroll
      for (int q = 0; q < 3; ++q) {
        bf16x8 af[4], bfr[4];
#pragma unroll
        for (int mt = 0; mt < 4; ++mt)   // A: W[f = f_off+mt*16+l15][c = quad*8+j]
          af[mt] = *(const bf16x8*)&ws[(q * 128 + f_off + mt * 16 + l15) * 40 + quad * 8];
#pragma unroll
        for (int nt = 0; nt < 4; ++nt) { // B: X[c][s]; s -> (r_out, w_out)
          int r_out = s_rowb + (nt >> 1);
          int w_out = (nt & 1) * 16 + l15;
          bfr[nt] = *(const bf16x8*)&xs[((r_out + p) * 34 + w_out + q) * 40 + quad * 8];
        }
#pragma unroll
        for (int mt = 0; mt < 4; ++mt)
#pragma unroll
          for (int nt = 0; nt < 4; ++nt)
            acc[mt][nt] = __builtin_amdgcn_mfma_f32_16x16x32_bf16(
                af[mt], bfr[nt], acc[mt][nt], 0, 0, 0);
      }
      __syncthreads();   // before ws (next p) / xs (next chunk) overwrite
    }
  }

  // ---- epilogue: C/D layout col=lane&15 (spatial w), row=quad*4+reg (f) ----
#pragma unroll
  for (int nt = 0; nt < 4; ++nt) {
    int h = h0 + s_rowb + (nt >> 1);
    int w_out = (nt & 1) * 16 + l15;
#pragma unroll
    for (int mt = 0; mt < 4; ++mt) {
#pragma unroll
      for (int reg = 0; reg < 4; ++reg) {
        int f = f_off + mt * 16 + quad * 4 + reg;
        out[((n_img * 128 + f) * 32 + h) * 32 + w_out] = acc[mt][nt][reg] + bias[f];
      }
    }
  }
}

// ---------------------------------------------------------------------------
extern "C" void kernel_launch(void* const* d_in, const int* in_sizes, int n_in,
                              void* d_out, int out_size, void* d_ws, size_t ws_size,
                              hipStream_t stream) {
  const float* x    = (const float*)d_in[0];   // 32*128*32*32
  const float* w    = (const float*)d_in[1];   // 128*128*3*3
  const float* bias = (const float*)d_in[2];   // 128
  float* out = (float*)d_out;                  // 32*128*32*32
  short* bc  = (short*)d_ws;                   // 368,640 B bf16 weight layout

  conv_wprep<<<576, 256, 0, stream>>>(w, bc);
  conv_main<<<256, 256, 0, stream>>>(x, bc, bias, out);
}

// Round 2
// 95.408 us; speedup vs baseline: 1.0366x; 1.0366x over previous
//
#include <hip/hip_runtime.h>

// ---------------------------------------------------------------------------
// Conv2dfft == 3x3 SAME cross-correlation conv (pad=1) + bias.
// N=32, C=128, F=128, H=W=32.  Implicit-GEMM, bf16 MFMA 16x16x32.
// Round 2: weights go global->VGPR (fragment-major prepass layout, no LDS);
// x double-buffered in LDS per 32-channel chunk; 5 barriers total.
// ---------------------------------------------------------------------------

typedef short bf16x8 __attribute__((ext_vector_type(8)));   // 8 bf16 (4 VGPR)
typedef short bf16x4 __attribute__((ext_vector_type(4)));   // 4 bf16 (2 VGPR)
typedef float f32x4  __attribute__((ext_vector_type(4)));   // MFMA 16x16 acc

__device__ __forceinline__ short f2bf(float f) {            // RNE fp32->bf16
  unsigned u = __builtin_bit_cast(unsigned, f);
  u = (u + 0x7fffu + ((u >> 16) & 1u)) >> 16;
  return (short)u;
}

// ---------------------------------------------------------------------------
// Prepass: weight (F,C,3,3) fp32 -> bf16 fragment-major layout:
//   bc2[chunk(4)][tap(9)][fblk(8)][lane(64)][j(8)]
// where lane = quad*16 + l15, A-frag element = W[f=fblk*16+l15][c=chunk*32+quad*8+j].
// Main kernel then loads one A-fragment as ONE coalesced global_load_dwordx4
// at (uniform base + lane*16) -- no LDS round trip for weights.
// 147456 elements -> 576 blocks x 256 threads, coalesced b16 stores.
// ---------------------------------------------------------------------------
__global__ __launch_bounds__(256) void conv_wprep(const float* __restrict__ w,
                                                  short* __restrict__ bc2) {
  int tid  = blockIdx.x * 256 + threadIdx.x;   // [0, 147456)
  int j    = tid & 7;
  int l15  = (tid >> 3) & 15;
  int quad = (tid >> 7) & 3;
  int fblk = (tid >> 9) & 7;
  int g2   = tid >> 12;                        // chunk*9 + tap, [0,36)
  int chunk = g2 / 9, tap = g2 % 9;
  int p = tap / 3, q = tap % 3;
  int f = fblk * 16 + l15;
  int c = chunk * 32 + quad * 8 + j;
  bc2[tid] = f2bf(w[(f * 128 + c) * 9 + p * 3 + q]);
}

// ---------------------------------------------------------------------------
// Main kernel: 256 blocks (1/CU) x 256 threads (4 waves, 1/SIMD).
// Block = image n_img, output rows h0..h0+3, all 32 cols, all 128 f.
// Wave: f_off=(wv&1)*64, row base=(wv>>1)*2; 4x4 acc of 16x16 tiles.
// Chunk loop (c in steps of 32): double-buffered xs, one barrier per chunk.
// ---------------------------------------------------------------------------
__global__ __launch_bounds__(256, 1) void conv_main(
    const float* __restrict__ x, const short* __restrict__ bc2,
    const float* __restrict__ bias, float* __restrict__ out) {
  // xs[buf][row(6)][col(34)][c(32 + 4 pad)] ; stride 36 shorts = 18 dwords
  // -> bfr read banks (18*col + 4*quad) % 32: exactly 2-way aliased (free).
  __shared__ __align__(16) short xs[2][6 * 34 * 36];      // 29376 B

  const int t    = threadIdx.x;
  const int lane = t & 63;
  const int wv   = t >> 6;
  const int n_img = blockIdx.x >> 3;
  const int h0    = (blockIdx.x & 7) << 2;

  const int l15  = lane & 15;
  const int quad = lane >> 4;
  const int f_off  = (wv & 1) * 64;
  const int s_rowb = (wv >> 1) * 2;

  // x staging mapping: w_ = t&31 (coalesced), g = t>>5 in [0,8) -> c-quad
  const int w_ = t & 31;
  const int g  = t >> 5;
  const float* xb = x + n_img * 128 * 1024;   // [c][h][w] for this image

  // Zero halo cols (col 0 == w=-1, col 33 == w=32) in BOTH buffers, once.
  if (t < 192) {
    int buf = t / 96, rem = t % 96;
    int r = rem / 16, rem2 = rem % 16;
    int colsel = rem2 / 8, q4 = rem2 % 8;
    *(int2*)&xs[buf][(r * 34 + colsel * 33) * 36 + q4 * 4] = make_int2(0, 0);
  }

  f32x4 acc[4][4] = {};
  float xv[24];

  // ---- load chunk 0 x into regs, stage to buf 0 ----
#pragma unroll
  for (int r = 0; r < 6; ++r) {
    int hr = h0 - 1 + r;
    bool ok = (unsigned)hr < 32u;
#pragma unroll
    for (int cc = 0; cc < 4; ++cc)
      xv[r * 4 + cc] = ok ? xb[((g * 4 + cc) * 32 + hr) * 32 + w_] : 0.f;
  }
#pragma unroll
  for (int r = 0; r < 6; ++r) {
    bf16x4 v = { f2bf(xv[r*4+0]), f2bf(xv[r*4+1]), f2bf(xv[r*4+2]), f2bf(xv[r*4+3]) };
    *(bf16x4*)&xs[0][(r * 34 + w_ + 1) * 36 + g * 4] = v;
  }
  __syncthreads();

#pragma unroll
  for (int chunk = 0; chunk < 4; ++chunk) {
    // ---- prefetch next chunk's x into regs (latency hides under MFMAs) ----
    if (chunk < 3) {
#pragma unroll
      for (int r = 0; r < 6; ++r) {
        int hr = h0 - 1 + r;
        bool ok = (unsigned)hr < 32u;
#pragma unroll
        for (int cc = 0; cc < 4; ++cc)
          xv[r * 4 + cc] =
              ok ? xb[(((chunk + 1) * 32 + g * 4 + cc) * 32 + hr) * 32 + w_] : 0.f;
      }
    }
    // ---- compute this chunk: 9 taps, A-frags straight from global (L2) ----
    const short* xbuf = xs[chunk & 1];
#pragma unroll
    for (int p = 0; p < 3; ++p) {
#pragma unroll
      for (int q = 0; q < 3; ++q) {
        const int tap = p * 3 + q;
        const short* wb = bc2 + ((chunk * 9 + tap) * 8 + (wv & 1) * 4) * 512;
        bf16x8 af[4], bfr[4];
#pragma unroll
        for (int mt = 0; mt < 4; ++mt)
          af[mt] = *(const bf16x8*)&wb[mt * 512 + lane * 8];  // coalesced dwordx4
#pragma unroll
        for (int nt = 0; nt < 4; ++nt) {
          int r   = s_rowb + (nt >> 1) + p;
          int col = (nt & 1) * 16 + l15 + q;
          bfr[nt] = *(const bf16x8*)&xbuf[(r * 34 + col) * 36 + quad * 8];
        }
#pragma unroll
        for (int mt = 0; mt < 4; ++mt)
#pragma unroll
          for (int nt = 0; nt < 4; ++nt)
            acc[mt][nt] = __builtin_amdgcn_mfma_f32_16x16x32_bf16(
                af[mt], bfr[nt], acc[mt][nt], 0, 0, 0);
      }
    }
    // ---- stage prefetched x into the other buffer, one barrier per chunk ----
    if (chunk < 3) {
#pragma unroll
      for (int r = 0; r < 6; ++r) {
        bf16x4 v = { f2bf(xv[r*4+0]), f2bf(xv[r*4+1]), f2bf(xv[r*4+2]), f2bf(xv[r*4+3]) };
        *(bf16x4*)&xs[(chunk + 1) & 1][(r * 34 + w_ + 1) * 36 + g * 4] = v;
      }
      __syncthreads();
    }
  }

  // ---- epilogue: C/D layout col=lane&15 (w), row=quad*4+reg (f) ----
#pragma unroll
  for (int nt = 0; nt < 4; ++nt) {
    int h = h0 + s_rowb + (nt >> 1);
    int w_out = (nt & 1) * 16 + l15;
#pragma unroll
    for (int mt = 0; mt < 4; ++mt) {
#pragma unroll
      for (int reg = 0; reg < 4; ++reg) {
        int f = f_off + mt * 16 + quad * 4 + reg;
        out[((n_img * 128 + f) * 32 + h) * 32 + w_out] = acc[mt][nt][reg] + bias[f];
      }
    }
  }
}

// ---------------------------------------------------------------------------
extern "C" void kernel_launch(void* const* d_in, const int* in_sizes, int n_in,
                              void* d_out, int out_size, void* d_ws, size_t ws_size,
                              hipStream_t stream) {
  const float* x    = (const float*)d_in[0];   // 32*128*32*32
  const float* w    = (const float*)d_in[1];   // 128*128*3*3
  const float* bias = (const float*)d_in[2];   // 128
  float* out = (float*)d_out;                  // 32*128*32*32
  short* bc2 = (short*)d_ws;                   // 294,912 B fragment-major weights

  conv_wprep<<<576, 256, 0, stream>>>(w, bc2);
  conv_main<<<256, 256, 0, stream>>>(x, bc2, bias, out);
}

// Round 3
// 87.482 us; speedup vs baseline: 1.1306x; 1.0906x over previous
//
#include <hip/hip_runtime.h>

// ---------------------------------------------------------------------------
// Conv2dfft == 3x3 SAME cross-correlation conv (pad=1) + bias.
// N=32, C=128, F=128, H=W=32.  Implicit-GEMM, bf16 MFMA 16x16x32.
// Round 3: af fragments double-buffered (prefetch group g+1 before group g's
// MFMAs, loads stay in flight across barriers); xs stride 40 shorts (16-B
// aligned -> true ds_read_b128, conflict-free); coalesced wprep reads.
// ---------------------------------------------------------------------------

typedef short bf16x8 __attribute__((ext_vector_type(8)));   // 8 bf16 (4 VGPR)
typedef short bf16x4 __attribute__((ext_vector_type(4)));   // 4 bf16 (2 VGPR)
typedef float f32x4  __attribute__((ext_vector_type(4)));   // MFMA 16x16 acc

__device__ __forceinline__ short f2bf(float f) {            // RNE fp32->bf16
  unsigned u = __builtin_bit_cast(unsigned, f);
  u = (u + 0x7fffu + ((u >> 16) & 1u)) >> 16;
  return (short)u;
}

// ---------------------------------------------------------------------------
// Prepass: weight (F,C,3,3) fp32 -> bf16 fragment-major:
//   bc2[chunk(4)*9+tap][fblk(8)][lane(64)][j(8)]
// A-frag element j of lane (quad*16+l15) = W[f=fblk*16+l15][c=chunk*32+quad*8+j].
// Coalesced READ (tid = linear w index), scattered 2-B writes (L2 absorbs).
// ---------------------------------------------------------------------------
__global__ __launch_bounds__(256) void conv_wprep(const float* __restrict__ w,
                                                  short* __restrict__ bc2) {
  int tid = blockIdx.x * 256 + threadIdx.x;    // [0, 147456)
  float v = w[tid];                            // coalesced
  int f   = tid / 1152;                        // w layout: f*1152 + c*9 + tap
  int rem = tid - f * 1152;
  int c   = rem / 9;
  int tap = rem - c * 9;
  int dst = ((((c >> 5) * 9 + tap) * 8 + (f >> 4)) * 512)   // [chunk*9+tap][fblk]
          + (((c >> 3) & 3) * 16 + (f & 15)) * 8            // lane = quad*16+l15
          + (c & 7);                                        // j
  bc2[dst] = f2bf(v);
}

// ---------------------------------------------------------------------------
// Main: 256 blocks (1/CU) x 256 threads (4 waves).
// Block = image n_img, output rows h0..h0+3, 32 cols, 128 f.
// Wave: f_off=(wv&1)*64, row base=(wv>>1)*2; 4x4 acc of 16x16 tiles.
// ---------------------------------------------------------------------------
__device__ __forceinline__ void load_af(bf16x8* dst, const short* __restrict__ bc2,
                                        int chunk, int p, int fsel, int lane) {
  const short* base = bc2 + (((chunk * 9 + p * 3) * 8 + fsel * 4) * 512) + lane * 8;
#pragma unroll
  for (int q = 0; q < 3; ++q)
#pragma unroll
    for (int mt = 0; mt < 4; ++mt)
      dst[q * 4 + mt] = *(const bf16x8*)(base + (q * 8 + mt) * 512);  // dwordx4
}

__global__ __launch_bounds__(256, 1) void conv_main(
    const float* __restrict__ x, const short* __restrict__ bc2,
    const float* __restrict__ bias, float* __restrict__ out) {
  // xs[buf][row(6)][col(34)][c(32 + 8 pad)] ; stride 40 shorts = 80 B:
  //  - bf16x8 reads at byte off 80*idx + 16*quad -> 16-B aligned (ds_read_b128)
  //  - bank starts (20*col + 4*quad) mod 32: every bank serves exactly 8
  //    accesses per wave b128 = the wave64 minimum -> conflict-free.
  __shared__ __align__(16) short xs[2][6 * 34 * 40];      // 32640 B

  const int t    = threadIdx.x;
  const int lane = t & 63;
  const int wv   = t >> 6;
  const int n_img = blockIdx.x >> 3;
  const int h0    = (blockIdx.x & 7) << 2;

  const int l15  = lane & 15;
  const int quad = lane >> 4;
  const int fsel   = wv & 1;
  const int f_off  = fsel * 64;
  const int s_rowb = (wv >> 1) * 2;

  const int w_ = t & 31;          // output col staged by this thread (coalesced)
  const int g  = t >> 5;          // c-quad group [0,8)
  const float* xb = x + n_img * 128 * 1024;

  // af double-buffer: group g = chunk*3+p, 12 frags (48 VGPRs) each.
  bf16x8 afA[12], afB[12];
  load_af(afA, bc2, 0, 0, fsel, lane);   // group 0 in flight ASAP

  // Zero halo cols (col 0 == w=-1, col 33 == w=32) in BOTH buffers, once.
  if (t < 192) {
    int buf = t / 96, rem = t % 96;
    int r = rem / 16, rem2 = rem % 16;
    int colsel = rem2 / 8, q4 = rem2 % 8;
    *(int2*)&xs[buf][(r * 34 + colsel * 33) * 40 + q4 * 4] = make_int2(0, 0);
  }

  f32x4 acc[4][4] = {};
  float xv[24];

  // ---- chunk 0 x -> regs -> buf 0 ----
#pragma unroll
  for (int r = 0; r < 6; ++r) {
    int hr = h0 - 1 + r;
    bool ok = (unsigned)hr < 32u;
#pragma unroll
    for (int cc = 0; cc < 4; ++cc)
      xv[r * 4 + cc] = ok ? xb[((g * 4 + cc) * 32 + hr) * 32 + w_] : 0.f;
  }
#pragma unroll
  for (int r = 0; r < 6; ++r) {
    bf16x4 v = { f2bf(xv[r*4+0]), f2bf(xv[r*4+1]), f2bf(xv[r*4+2]), f2bf(xv[r*4+3]) };
    *(bf16x4*)&xs[0][(r * 34 + w_ + 1) * 40 + g * 4] = v;
  }
  __syncthreads();

#pragma unroll
  for (int chunk = 0; chunk < 4; ++chunk) {
    // ---- prefetch next chunk's x into regs (hides under 144 MFMAs) ----
    if (chunk < 3) {
#pragma unroll
      for (int r = 0; r < 6; ++r) {
        int hr = h0 - 1 + r;
        bool ok = (unsigned)hr < 32u;
#pragma unroll
        for (int cc = 0; cc < 4; ++cc)
          xv[r * 4 + cc] =
              ok ? xb[(((chunk + 1) * 32 + g * 4 + cc) * 32 + hr) * 32 + w_] : 0.f;
      }
    }
    const short* xbuf = xs[chunk & 1];
#pragma unroll
    for (int p = 0; p < 3; ++p) {
      const int grp = chunk * 3 + p;
      const bf16x8* cur = (grp & 1) ? afB : afA;
      bf16x8*       nxt = (grp & 1) ? afA : afB;
      if (grp < 11)                       // prefetch next af group (may cross
        load_af(nxt, bc2, (grp + 1) / 3, (grp + 1) % 3, fsel, lane);  // barrier)
#pragma unroll
      for (int q = 0; q < 3; ++q) {
        bf16x8 bfr[4];
#pragma unroll
        for (int nt = 0; nt < 4; ++nt) {
          int r   = s_rowb + (nt >> 1) + p;
          int col = (nt & 1) * 16 + l15 + q;
          bfr[nt] = *(const bf16x8*)&xbuf[(r * 34 + col) * 40 + quad * 8];
        }
#pragma unroll
        for (int mt = 0; mt < 4; ++mt)
#pragma unroll
          for (int nt = 0; nt < 4; ++nt)
            acc[mt][nt] = __builtin_amdgcn_mfma_f32_16x16x32_bf16(
                cur[q * 4 + mt], bfr[nt], acc[mt][nt], 0, 0, 0);
      }
    }
    // ---- stage prefetched x into the other buffer ----
    if (chunk < 3) {
#pragma unroll
      for (int r = 0; r < 6; ++r) {
        bf16x4 v = { f2bf(xv[r*4+0]), f2bf(xv[r*4+1]), f2bf(xv[r*4+2]), f2bf(xv[r*4+3]) };
        *(bf16x4*)&xs[(chunk + 1) & 1][(r * 34 + w_ + 1) * 40 + g * 4] = v;
      }
      __syncthreads();
    }
  }

  // ---- epilogue: C/D layout col=lane&15 (w), row=quad*4+reg (f) ----
#pragma unroll
  for (int nt = 0; nt < 4; ++nt) {
    int h = h0 + s_rowb + (nt >> 1);
    int w_out = (nt & 1) * 16 + l15;
#pragma unroll
    for (int mt = 0; mt < 4; ++mt) {
#pragma unroll
      for (int reg = 0; reg < 4; ++reg) {
        int f = f_off + mt * 16 + quad * 4 + reg;
        out[((n_img * 128 + f) * 32 + h) * 32 + w_out] = acc[mt][nt][reg] + bias[f];
      }
    }
  }
}

// ---------------------------------------------------------------------------
extern "C" void kernel_launch(void* const* d_in, const int* in_sizes, int n_in,
                              void* d_out, int out_size, void* d_ws, size_t ws_size,
                              hipStream_t stream) {
  const float* x    = (const float*)d_in[0];   // 32*128*32*32
  const float* w    = (const float*)d_in[1];   // 128*128*3*3
  const float* bias = (const float*)d_in[2];   // 128
  float* out = (float*)d_out;                  // 32*128*32*32
  short* bc2 = (short*)d_ws;                   // 294,912 B fragment-major weights

  conv_wprep<<<576, 256, 0, stream>>>(w, bc2);
  conv_main<<<256, 256, 0, stream>>>(x, bc2, bias, out);
}